// Round 13
// baseline (171.715 us; speedup 1.0000x reference)
//
#include <hip/hip_runtime.h>
#include <math.h>

#define D_MODEL 1024
#define NHEAD 16
#define HD 64
#define SEQ 2048
#define BATCH 2
#define MTOT (BATCH * SEQ)  // 4096

typedef __attribute__((ext_vector_type(8))) short bf16x8;
typedef __attribute__((ext_vector_type(4))) float f32x4;

__device__ __forceinline__ unsigned short f2bf(float f) {
    unsigned int u = __float_as_uint(f);
    u += 0x7FFF + ((u >> 16) & 1);  // round-to-nearest-even
    return (unsigned short)(u >> 16);
}

// packed f32x2 -> bf16x2 via HW cvt (RNE, bit-identical to f2bf for normals)
__device__ __forceinline__ unsigned int pk2bf(float a, float b) {
    unsigned int r;
    asm("v_cvt_pk_bf16_f32 %0, %1, %2" : "=v"(r) : "v"(a), "v"(b));
    return r;
}

// async global->LDS, 16B per lane. lds must be the wave-uniform chunk base:
// HW writes lane's 16B to base + lane*16 (guide §5 caveat).
__device__ __forceinline__ void async16(unsigned short* lds, const unsigned short* g) {
    __builtin_amdgcn_global_load_lds(
        (const __attribute__((address_space(1))) unsigned int*)g,
        (__attribute__((address_space(3))) unsigned int*)lds, 16, 0, 0);
}

// raw barrier with compiler memory fence (no vmcnt drain, unlike __syncthreads)
__device__ __forceinline__ void BAR() {
    asm volatile("" ::: "memory");
    __builtin_amdgcn_s_barrier();
    asm volatile("" ::: "memory");
}

// ---------------------------------------------------------------------------
// Fused prep: blocks [0,4096) convert x fp32->bf16; blocks [4096,8192)
// transpose the 4 weights W[k][n] fp32 -> Wt[n][k] bf16.
// ---------------------------------------------------------------------------
__global__ __launch_bounds__(256) void prep(const float* __restrict__ x,
                                            unsigned short* __restrict__ xb,
                                            const float* __restrict__ W0,
                                            const float* __restrict__ W1,
                                            const float* __restrict__ W2,
                                            const float* __restrict__ W3,
                                            unsigned short* __restrict__ Wt) {
    const int bid = blockIdx.x;
    const int tid = threadIdx.x;
    if (bid < 4096) {
        const int i = (bid * 256 + tid) * 4;
        float4 v = *(const float4*)(x + i);
        uint2 pk;
        pk.x = pk2bf(v.x, v.y);
        pk.y = pk2bf(v.z, v.w);
        *(uint2*)(xb + i) = pk;
    } else {
        __shared__ float T[32][33];
        const int t = bid - 4096;
        const int z = t >> 10, rem = t & 1023;
        const int n0 = (rem & 31) * 32, k0 = (rem >> 5) * 32;
        const float* W = (z == 0) ? W0 : (z == 1) ? W1 : (z == 2) ? W2 : W3;
        unsigned short* out = Wt + (size_t)z * D_MODEL * D_MODEL;
        const int tx = tid & 31, ty = tid >> 5;
#pragma unroll
        for (int i = 0; i < 4; ++i)
            T[ty + 8 * i][tx] = W[(size_t)(k0 + ty + 8 * i) * D_MODEL + n0 + tx];
        __syncthreads();
#pragma unroll
        for (int i = 0; i < 4; ++i)
            out[(size_t)(n0 + ty + 8 * i) * D_MODEL + k0 + tx] = f2bf(T[tx][ty + 8 * i]);
    }
}

// ---------------------------------------------------------------------------
// Fused QKV GEMM: 128x192 tile, 8-barrier-per-tile phase rhythm.
// (Round-9 verified.) Grid 32x16 = 512 blocks = 2 blocks/CU, 512 thr.
// ---------------------------------------------------------------------------
__global__ __launch_bounds__(512, 2) void qkv_mfma(const unsigned short* __restrict__ A,
                                                   const unsigned short* __restrict__ Wt,
                                                   unsigned short* __restrict__ q,
                                                   unsigned short* __restrict__ k,
                                                   unsigned short* __restrict__ vt) {
    __shared__ unsigned short SM[40960];  // 80 KB
    const int tid = threadIdx.x;
    const int wave = tid >> 6, lane = tid & 63;
    const int quad = lane >> 4, l16 = lane & 15;
    const int wm = wave >> 2, wn = wave & 3;

    // XCD-chunked block swizzle (512 % 8 == 0 -> bijective)
    const int bid = blockIdx.x;
    const int swz = (bid & 7) * 64 + (bid >> 3);
    const int by = swz >> 4, bx = swz & 15;
    const int m0 = by * 128;
    const int c0 = bx * 192;  // column base within [3072]
    const unsigned short* Bz = Wt;  // Wt viewed as one [3072][1024]

    // ---- staging descriptors (source chunk pre-swizzled) ----
    const unsigned short* aptr;
    {
        const int s = tid, r = s >> 2;
        const int cg = (s & 3) ^ ((r + (r >> 2)) & 3);
        aptr = A + (size_t)(m0 + r) * D_MODEL + cg * 8;
    }
    const unsigned short* bptr[2];
#pragma unroll
    for (int j = 0; j < 2; ++j) {
        const int s = j * 512 + tid;
        const int r = s >> 2;
        const int cg = (s & 3) ^ ((r + (r >> 2)) & 3);
        const int rb = (r < 192) ? r : 191;  // j=1 used only by tid<256
        bptr[j] = Bz + (size_t)(c0 + rb) * D_MODEL + cg * 8;
    }
    const int ldsA0 = wave * 512;                 // ushort units
    const int ldsB0 = wave * 512, ldsB1 = 4096 + wave * 512;

    // ---- fragment read offsets (swizzled; key matches staging) ----
    const int key = (l16 + (l16 >> 2)) & 3;
    const int chunk = quad ^ key;
    int aoff[4], boff[3];
#pragma unroll
    for (int mt = 0; mt < 4; ++mt)
        aoff[mt] = ((wm * 64 + mt * 16 + l16) * 4 + chunk) * 8;
#pragma unroll
    for (int nt = 0; nt < 3; ++nt)
        boff[nt] = ((wn * 48 + nt * 16 + l16) * 4 + chunk) * 8;

    f32x4 acc[4][3];
#pragma unroll
    for (int mt = 0; mt < 4; ++mt)
#pragma unroll
        for (int nt = 0; nt < 3; ++nt)
            acc[mt][nt] = (f32x4){0.f, 0.f, 0.f, 0.f};

    auto stageA = [&](int d, int ks, int T) {
        const int base = d * 20480 + ks * 4096;
        async16(SM + base + ldsA0, aptr + T * 64 + ks * 32);
    };
    auto stageB = [&](int d, int ks, int T) {
        const int base = d * 20480 + 8192 + ks * 6144;
        async16(SM + base + ldsB0, bptr[0] + T * 64 + ks * 32);
        if (wave < 4)
            async16(SM + base + ldsB1, bptr[1] + T * 64 + ks * 32);
    };
    auto dsA = [&](bf16x8* af, int mh, int d, int ks) {
        const int base = d * 20480 + ks * 4096;
#pragma unroll
        for (int i = 0; i < 2; ++i)
            af[i] = *(const bf16x8*)&SM[base + aoff[mh * 2 + i]];
    };
    auto dsB = [&](bf16x8* bf, int d, int ks) {
        const int base = d * 20480 + 8192 + ks * 6144;
#pragma unroll
        for (int i = 0; i < 3; ++i)
            bf[i] = *(const bf16x8*)&SM[base + boff[i]];
    };
    auto mfma6 = [&](bf16x8* af, bf16x8* bf, int mh) {
        __builtin_amdgcn_s_setprio(1);
#pragma unroll
        for (int i = 0; i < 2; ++i)
#pragma unroll
            for (int nt = 0; nt < 3; ++nt)
                acc[mh * 2 + i][nt] = __builtin_amdgcn_mfma_f32_16x16x32_bf16(
                    af[i], bf[nt], acc[mh * 2 + i][nt], 0, 0, 0);
        __builtin_amdgcn_s_setprio(0);
    };
    auto waitc = [&](bool nx) {
        if (nx) {
            if (wave < 4) asm volatile("s_waitcnt vmcnt(3)" ::: "memory");
            else          asm volatile("s_waitcnt vmcnt(2)" ::: "memory");
        } else {
            asm volatile("s_waitcnt vmcnt(0)" ::: "memory");
        }
    };

    // ---- prologue: stage tile 0 (A0,B0,A1,B1), retire A0+B0, sync ----
    stageA(0, 0, 0);
    stageB(0, 0, 0);
    stageA(0, 1, 0);
    stageB(0, 1, 0);
    waitc(true);
    BAR();

    const int NT = D_MODEL / 64;  // 16
    for (int T = 0; T < NT; ++T) {
        const int d = T & 1, dn = d ^ 1;
        const bool nx = (T + 1 < NT);
        bf16x8 af[2], bf[3];
        // ph1: reads (mh0,ks0); stage A-half0(T+1); BAR; MFMA; BAR
        dsA(af, 0, d, 0);
        dsB(bf, d, 0);
        if (nx) stageA(dn, 0, T + 1);
        __builtin_amdgcn_sched_barrier(0);
        BAR();
        mfma6(af, bf, 0);
        BAR();
        // ph2: reads (mh1,ks0) reuse bf; stage B-half0(T+1); gate A1,B1(T)
        dsA(af, 1, d, 0);
        if (nx) stageB(dn, 0, T + 1);
        waitc(nx);
        __builtin_amdgcn_sched_barrier(0);
        BAR();
        mfma6(af, bf, 1);
        BAR();
        // ph3: reads (mh0,ks1); stage A-half1(T+1); BAR; MFMA; BAR
        dsA(af, 0, d, 1);
        dsB(bf, d, 1);
        if (nx) stageA(dn, 1, T + 1);
        __builtin_amdgcn_sched_barrier(0);
        BAR();
        mfma6(af, bf, 0);
        BAR();
        // ph4: reads (mh1,ks1); stage B-half1(T+1); gate A0,B0(T+1)
        dsA(af, 1, d, 1);
        if (nx) stageB(dn, 1, T + 1);
        waitc(nx);
        __builtin_amdgcn_sched_barrier(0);
        BAR();
        mfma6(af, bf, 1);
        BAR();
    }

    // ---- epilogue: 3 x 64-col groups; QK path or V^T path per group ----
    __syncthreads();
    const int bb = m0 >> 11, tok0 = m0 & (SEQ - 1);
#pragma unroll 1
    for (int G = 0; G < 3; ++G) {
        if (G) __syncthreads();
        const int gcol = c0 + G * 64;
        const int zg = gcol >> 10;
        const int hg = (gcol >> 6) & 15;
        if (zg < 2) {
            const float sc = (zg == 0) ? 0.18033688011112042f : 1.0f;  // 0.125*log2(e)
            unsigned short* dst = (zg == 0) ? q : k;
            // stage [128 tok][64 d]
#pragma unroll
            for (int nt = 0; nt < 3; ++nt) {
                const int colb = wn * 48 + nt * 16;
                if ((colb >> 6) == G) {
                    const int cl = colb - G * 64 + l16;
#pragma unroll
                    for (int mt = 0; mt < 4; ++mt)
#pragma unroll
                        for (int reg = 0; reg < 4; ++reg) {
                            const int rr = wm * 64 + mt * 16 + quad * 4 + reg;
                            SM[rr * 64 + cl] = f2bf(acc[mt][nt][reg] * sc);
                        }
                }
            }
            __syncthreads();
#pragma unroll
            for (int it = 0; it < 2; ++it) {
                const int g = it * 512 + tid;
                const int r = g >> 3, c8 = g & 7;
                uint4 val = *(const uint4*)&SM[r * 64 + c8 * 8];
                *(uint4*)(dst + (((size_t)bb * NHEAD + hg) * SEQ + tok0 + r) * HD +
                          c8 * 8) = val;
            }
        } else {
            // V^T: stage [64 d][128 tok + pad 8]
#pragma unroll
            for (int nt = 0; nt < 3; ++nt) {
                const int colb = wn * 48 + nt * 16;
                if ((colb >> 6) == G) {
                    const int dl = colb - G * 64 + l16;
#pragma unroll
                    for (int mt = 0; mt < 4; ++mt) {
                        const int m = wm * 64 + mt * 16 + quad * 4;
                        uint2 w;
                        w.x = pk2bf(acc[mt][nt][0], acc[mt][nt][1]);
                        w.y = pk2bf(acc[mt][nt][2], acc[mt][nt][3]);
                        *(uint2*)&SM[dl * 136 + m] = w;
                    }
                }
            }
            __syncthreads();
#pragma unroll
            for (int it = 0; it < 2; ++it) {
                const int g = it * 512 + tid;
                const int dd = g >> 4, t8 = (g & 15) * 8;
                uint4 val = *(const uint4*)&SM[dd * 136 + t8];
                *(uint4*)(vt + (((size_t)bb * NHEAD + hg) * HD + dd) * SEQ + tok0 +
                          t8) = val;
            }
        }
    }
}

// ---------------------------------------------------------------------------
// bf16 MFMA GEMM (output projection only): 64x128 tile, BK=64, 4 waves.
// Grid (8,64) = 512 blocks = 2 blocks/CU (round-8 verified win).
// ---------------------------------------------------------------------------
__global__ __launch_bounds__(256) void gemm_out(const unsigned short* __restrict__ A,
                                                const unsigned short* __restrict__ Bw,
                                                float* __restrict__ outf) {
    __shared__ unsigned short SM[12288];  // As = [0,4096), Bs = [4096,12288)
    const int tid = threadIdx.x;
    const int m0 = blockIdx.y * 64, n0 = blockIdx.x * 128;
    const int wave = tid >> 6, lane = tid & 63;
    const int quad = lane >> 4, l16 = lane & 15;
    const int wm = wave & 1, wn = wave >> 1;  // wave tile: 32 rows x 64 cols

    f32x4 acc[2][4];
#pragma unroll
    for (int mt = 0; mt < 2; ++mt)
#pragma unroll
        for (int nt = 0; nt < 4; ++nt)
            acc[mt][nt] = (f32x4){0.f, 0.f, 0.f, 0.f};

    for (int k0 = 0; k0 < D_MODEL; k0 += 64) {
        __syncthreads();
        // A: 64 rows -> 512 chunks (2/thread); B: 128 rows -> 1024 (4/thread)
#pragma unroll
        for (int i = 0; i < 2; ++i) {
            const int c = i * 256 + tid;
            const int r = c >> 3, cc = (c & 7) * 8;
            const int cbase = i * 256 + wave * 64;  // wave-uniform chunk base
            async16(SM + cbase * 8, A + (size_t)(m0 + r) * D_MODEL + k0 + cc);
        }
#pragma unroll
        for (int i = 0; i < 4; ++i) {
            const int c = i * 256 + tid;
            const int r = c >> 3, cc = (c & 7) * 8;
            const int cbase = i * 256 + wave * 64;
            async16(SM + 4096 + cbase * 8, Bw + (size_t)(n0 + r) * D_MODEL + k0 + cc);
        }
        __syncthreads();
#pragma unroll
        for (int ks = 0; ks < 2; ++ks) {
            bf16x8 af[2], bfr[4];
#pragma unroll
            for (int mt = 0; mt < 2; ++mt)
                af[mt] = *(const bf16x8*)&SM[(wm * 32 + mt * 16 + l16) * 64 + ks * 32 + quad * 8];
#pragma unroll
            for (int nt = 0; nt < 4; ++nt)
                bfr[nt] = *(const bf16x8*)&SM[4096 + (wn * 64 + nt * 16 + l16) * 64 + ks * 32 + quad * 8];
#pragma unroll
            for (int mt = 0; mt < 2; ++mt)
#pragma unroll
                for (int nt = 0; nt < 4; ++nt)
                    acc[mt][nt] = __builtin_amdgcn_mfma_f32_16x16x32_bf16(
                        af[mt], bfr[nt], acc[mt][nt], 0, 0, 0);
        }
    }

#pragma unroll
    for (int mt = 0; mt < 2; ++mt)
#pragma unroll
        for (int nt = 0; nt < 4; ++nt)
#pragma unroll
            for (int reg = 0; reg < 4; ++reg) {
                const int m = m0 + wm * 32 + mt * 16 + quad * 4 + reg;
                const int n = n0 + wn * 64 + nt * 16 + l16;
                outf[(size_t)m * D_MODEL + n] = acc[mt][nt][reg];
            }
}

// ---------------------------------------------------------------------------
// MFMA flash attention (causal), Q-SPLIT + complementary p-mapping (round-11
// verified) + IN-REGISTER P EXCHANGE (this round): the P LDS round-trip
// (4 ds_write + lgkmcnt + 2 ds_read, ~150-200 serial cycles/iter) is
// replaced by 16 ds_bpermute + 8 cndmask. Derivation: lane (q=l16, quad)
// holds P[k=mt*16+quad*4+reg][q] (C-layout); the B-fragment needs
// P[k=ks*32+quad*8+j][q] — same q column, so word w of bP[ks] is
// u[2ks+(quad>>1)][w&1] taken from lane l16 + 32*(quad&1) + 16*(w>>1).
// Frees P's 8 KB LDS (40 -> 32 KB).
// ---------------------------------------------------------------------------
__global__ __launch_bounds__(256, 4) void attn_mfma(const unsigned short* __restrict__ Q,
                                                    const unsigned short* __restrict__ K,
                                                    const unsigned short* __restrict__ VT,
                                                    unsigned short* __restrict__ ctx) {
    // LDS (ushorts): K dbuf [0,4096)+[4096,8192); V dbuf [8192,12288)+
    // [12288,16384).
    __shared__ unsigned short SM[16384];  // 32 KB
    const int tid = threadIdx.x;
    const int wave = tid >> 6, lane = tid & 63;
    const int quad = lane >> 4, l16 = lane & 15;
    const int h = blockIdx.x, b = blockIdx.z;
    const int y = blockIdx.y;
    const int p = (y < 16) ? (31 - y) : (y - 16);  // complementary pairs
    const int row0 = p * 64;
    const int qrow = row0 + wave * 16 + l16;  // this lane's q-row
    const unsigned short* Qp = Q + ((size_t)b * NHEAD + h) * SEQ * HD;
    const unsigned short* Kp = K + ((size_t)b * NHEAD + h) * SEQ * HD;
    const unsigned short* Vp = VT + ((size_t)b * NHEAD + h) * HD * SEQ;
    const int sw8 = l16 & 7;  // K/V swizzle key (row & 7)

    // ---- staging descriptors: chunk c = j*256+tid covers LDS row r=c>>3,
    //      slot s=c&7; source holds global slot s^(r&7) (pre-swizzle) ----
    const unsigned short* kptr[2];
    const unsigned short* vptr[2];
    int ldsoff[2];
#pragma unroll
    for (int j = 0; j < 2; ++j) {
        const int c = j * 256 + tid;
        const int r = c >> 3, s = c & 7;
        const int sg = (s ^ (r & 7)) * 8;
        kptr[j] = Kp + (size_t)r * HD + sg;   // + kt*64*HD per tile
        vptr[j] = Vp + (size_t)r * SEQ + sg;  // + kt*64 per tile
        ldsoff[j] = (j * 256 + wave * 64) * 8;  // wave-uniform chunk base
    }
    auto stageKV = [&](int d, int kt) {
        const int kb = d * 4096, vb = 8192 + d * 4096;
#pragma unroll
        for (int j = 0; j < 2; ++j) {
            async16(SM + kb + ldsoff[j], kptr[j] + (size_t)kt * 64 * HD);
            async16(SM + vb + ldsoff[j], vptr[j] + kt * 64);
        }
    };

    // ---- Q fragment (one 16-row block per wave) ----
    bf16x8 bQ[2];
#pragma unroll
    for (int ks = 0; ks < 2; ++ks)
        bQ[ks] = *(const bf16x8*)(Qp + (size_t)qrow * HD + ks * 32 + quad * 8);

    f32x4 o[4];  // O^T accumulators: [d-tile]; lane value (d=nt*16+quad*4+reg, q=l16)
    float ps = 0.f;
#pragma unroll
    for (int nt = 0; nt < 4; ++nt)
        o[nt] = (f32x4){0.f, 0.f, 0.f, 0.f};

    // bpermute source-lane byte indices (w>>1 selects +16)
    const int bpx0 = (l16 + 32 * (quad & 1)) << 2;
    const int bpx1 = bpx0 + (16 << 2);

    // ---- prologue: stage tile 0 (vmcnt also covers the bQ loads) ----
    stageKV(0, 0);
    asm volatile("s_waitcnt vmcnt(0)" ::: "memory");
    BAR();

    for (int kt = 0; kt <= p; ++kt) {
        const int cur = kt & 1;
        const int kbase = cur * 4096, vbase = 8192 + cur * 4096;

        // ---- aK from shared K tile (swizzled ds_read_b128, 2-way free) ----
        bf16x8 aK[4][2];
#pragma unroll
        for (int mt = 0; mt < 4; ++mt)
#pragma unroll
            for (int ks = 0; ks < 2; ++ks)
                aK[mt][ks] = *(const bf16x8*)&SM[kbase + (mt * 16 + l16) * 64 +
                                                 (((ks * 4 + quad)) ^ sw8) * 8];

        // ---- issue next tile's staging early (lands under softmax+PV) ----
        if (kt < p) stageKV(cur ^ 1, kt + 1);

        // ---- S^T = K Q^T (m = k-row, n = q-row) ----
        f32x4 sT[4];
        __builtin_amdgcn_s_setprio(1);
#pragma unroll
        for (int mt = 0; mt < 4; ++mt) {
            sT[mt] = __builtin_amdgcn_mfma_f32_16x16x32_bf16(
                aK[mt][0], bQ[0], (f32x4){0.f, 0.f, 0.f, 0.f}, 0, 0, 0);
            sT[mt] = __builtin_amdgcn_mfma_f32_16x16x32_bf16(
                aK[mt][1], bQ[1], sT[mt], 0, 0, 0);
        }
        __builtin_amdgcn_s_setprio(0);

        // ---- exp2 + causal mask (diag tile only) + pack to bf16 pairs ----
        const bool diag = (kt == p);
        unsigned int u[4][2];  // u[mt][t] = bf16{P[k=mt*16+quad*4+2t], +1}
#pragma unroll
        for (int mt = 0; mt < 4; ++mt) {
            float pv[4];
#pragma unroll
            for (int reg = 0; reg < 4; ++reg)
                pv[reg] = __builtin_amdgcn_exp2f(sT[mt][reg]);
            if (diag) {
                const int kb = kt * 64 + mt * 16 + quad * 4;
#pragma unroll
                for (int reg = 0; reg < 4; ++reg)
                    pv[reg] = (kb + reg > qrow) ? 0.f : pv[reg];
            }
            ps += (pv[0] + pv[1]) + (pv[2] + pv[3]);
            u[mt][0] = pk2bf(pv[0], pv[1]);
            u[mt][1] = pk2bf(pv[2], pv[3]);
        }

        // ---- in-register P relayout: C-layout -> B-operand layout ----
        // word w of bP[ks] = u[2ks+(quad>>1)][w&1] from lane
        // l16 + 32*(quad&1) + 16*(w>>1). 16 bpermute + 8 selects.
        bf16x8 bP[2];
        const bool hi = (quad >= 2);
#pragma unroll
        for (int ks = 0; ks < 2; ++ks) {
            unsigned int w0, w1, w2, w3, ra, rb;
            ra = (unsigned int)__builtin_amdgcn_ds_bpermute(bpx0, (int)u[2 * ks + 0][0]);
            rb = (unsigned int)__builtin_amdgcn_ds_bpermute(bpx0, (int)u[2 * ks + 1][0]);
            w0 = hi ? rb : ra;
            ra = (unsigned int)__builtin_amdgcn_ds_bpermute(bpx0, (int)u[2 * ks + 0][1]);
            rb = (unsigned int)__builtin_amdgcn_ds_bpermute(bpx0, (int)u[2 * ks + 1][1]);
            w1 = hi ? rb : ra;
            ra = (unsigned int)__builtin_amdgcn_ds_bpermute(bpx1, (int)u[2 * ks + 0][0]);
            rb = (unsigned int)__builtin_amdgcn_ds_bpermute(bpx1, (int)u[2 * ks + 1][0]);
            w2 = hi ? rb : ra;
            ra = (unsigned int)__builtin_amdgcn_ds_bpermute(bpx1, (int)u[2 * ks + 0][1]);
            rb = (unsigned int)__builtin_amdgcn_ds_bpermute(bpx1, (int)u[2 * ks + 1][1]);
            w3 = hi ? rb : ra;
            uint4 pw = {w0, w1, w2, w3};
            bP[ks] = *(const bf16x8*)&pw;
        }

        // ---- aV from shared V tile + O^T += V^T P^T ----
        bf16x8 aV[4][2];
#pragma unroll
        for (int nt = 0; nt < 4; ++nt)
#pragma unroll
            for (int ks = 0; ks < 2; ++ks)
                aV[nt][ks] = *(const bf16x8*)&SM[vbase + (nt * 16 + l16) * 64 +
                                                 (((ks * 4 + quad)) ^ sw8) * 8];
        __builtin_amdgcn_s_setprio(1);
#pragma unroll
        for (int nt = 0; nt < 4; ++nt) {
            o[nt] = __builtin_amdgcn_mfma_f32_16x16x32_bf16(
                aV[nt][0], bP[0], o[nt], 0, 0, 0);
            o[nt] = __builtin_amdgcn_mfma_f32_16x16x32_bf16(
                aV[nt][1], bP[1], o[nt], 0, 0, 0);
        }
        __builtin_amdgcn_s_setprio(0);

        // ---- next tile staged + all waves done with cur ----
        asm volatile("s_waitcnt vmcnt(0)" ::: "memory");
        BAR();
    }

    // ---- row-sum reduce across quads (q lives in l16; partials in quads) --
    ps += __shfl_xor(ps, 16);
    ps += __shfl_xor(ps, 32);
    const float inv = 1.f / ps;

    // ---- direct store (no cross-wave combine: each wave owns its rows) ----
#pragma unroll
    for (int nt = 0; nt < 4; ++nt) {
        const int col = h * HD + nt * 16 + quad * 4;
        uint2 w;
        w.x = pk2bf(o[nt][0] * inv, o[nt][1] * inv);
        w.y = pk2bf(o[nt][2] * inv, o[nt][3] * inv);
        *(uint2*)(ctx + ((size_t)b * SEQ + qrow) * D_MODEL + col) = w;
    }
}

extern "C" void kernel_launch(void* const* d_in, const int* in_sizes, int n_in,
                              void* d_out, int out_size, void* d_ws, size_t ws_size,
                              hipStream_t stream) {
    const float* x  = (const float*)d_in[0];
    const float* Wq = (const float*)d_in[1];
    const float* Wk = (const float*)d_in[2];
    const float* Wv = (const float*)d_in[3];
    const float* Wo = (const float*)d_in[4];
    float* out = (float*)d_out;

    unsigned short* ws = (unsigned short*)d_ws;
    const size_t T = (size_t)MTOT * D_MODEL;  // 4,194,304 elements
    unsigned short* xb  = ws;                 // [4096,1024] bf16
    unsigned short* Wt  = ws + T;             // 4 x [1024,1024] bf16 (W^T)
    unsigned short* q   = ws + 2 * T;         // [B,H,N,64]  (pre-scaled)
    unsigned short* k   = ws + 3 * T;         // [B,H,N,64]
    unsigned short* vt  = ws + 4 * T;         // [B,H,64,N]
    unsigned short* ctx = ws + 5 * T;         // [4096,1024]

    prep<<<dim3(8192), dim3(256), 0, stream>>>(x, xb, Wq, Wk, Wv, Wo, Wt);

    qkv_mfma<<<dim3(512), dim3(512), 0, stream>>>(xb, Wt, q, k, vt);

    attn_mfma<<<dim3(NHEAD, 32, BATCH), dim3(256), 0, stream>>>(q, k, vt, ctx);

    gemm_out<<<dim3(8, 64), dim3(256), 0, stream>>>(ctx, Wt + 3 * (size_t)D_MODEL * D_MODEL, out);
}